// Round 1
// baseline (2597.665 us; speedup 1.0000x reference)
//
#include <hip/hip_runtime.h>
#include <hip/hip_bf16.h>

#define BB 8
#define CC 128
#define NN 4096  // H*W = 64*64

// ---------------------------------------------------------------------------
// conv1x1 input stage: out = w @ in + bias, per spatial position.
// in:  [B][C][N]  (channel-major, n contiguous)
// out: layout_nc==1 -> [B][N][C] ; layout_nc==0 -> [B][C][N]
// One block per (64-wide n tile, batch). 256 threads.
// ---------------------------------------------------------------------------
__global__ __launch_bounds__(256) void nl_conv_in(
    const float* __restrict__ in, const float* __restrict__ w,
    const float* __restrict__ bias, float* __restrict__ out, int layout_nc)
{
  __shared__ float sm[64 * 129];  // overlay: in_t[128][64] (8192) then out_t[64][129]
  const int b  = blockIdx.y;
  const int n0 = blockIdx.x * 64;
  const int t  = threadIdx.x;

#pragma unroll
  for (int k = 0; k < 32; ++k) {
    int flat = t + 256 * k;          // 8192 elements
    int c = flat >> 6, j = flat & 63;
    sm[c * 64 + j] = in[(size_t)b * CC * NN + (size_t)c * NN + n0 + j];
  }
  __syncthreads();

  const int j = t & 63, wq = t >> 6;  // wave-uniform wq
  float acc[32];
#pragma unroll
  for (int g = 0; g < 32; ++g) acc[g] = bias[wq * 32 + g];
  for (int cp = 0; cp < 128; ++cp) {
    float v = sm[cp * 64 + j];        // lanes j -> conflict-free
#pragma unroll
    for (int g = 0; g < 32; ++g)
      acc[g] += w[(wq * 32 + g) * CC + cp] * v;  // wave-uniform w read
  }
  __syncthreads();
#pragma unroll
  for (int g = 0; g < 32; ++g) sm[j * 129 + wq * 32 + g] = acc[g];  // (j+c)%32 spread
  __syncthreads();

  if (layout_nc) {
#pragma unroll
    for (int k = 0; k < 32; ++k) {
      int flat = t + 256 * k;
      int c = flat & 127, jj = flat >> 7;
      out[(size_t)b * NN * CC + (size_t)(n0 + jj) * CC + c] = sm[jj * 129 + c];
    }
  } else {
#pragma unroll
    for (int k = 0; k < 32; ++k) {
      int flat = t + 256 * k;
      int jj = flat & 63, c = flat >> 6;
      out[(size_t)b * CC * NN + (size_t)c * NN + n0 + jj] = sm[jj * 129 + c];
    }
  }
}

// ---------------------------------------------------------------------------
// Pass 1: per-column (axis-1 / ref-position) softmax stats.
// s[n,m] = sum_c X[n,c]*Y[c,m];  Mc[m] = max_n s ; Lc[m] = sum_n exp(s-Mc).
// One block per (64-wide m tile, batch); loops over all 64 n tiles with an
// online (M,L) merge. S never materialized.
// ---------------------------------------------------------------------------
__global__ __launch_bounds__(256) void nl_stats(
    const float* __restrict__ X,   // [B][N][C]
    const float* __restrict__ Y,   // [B][C][N]
    float* __restrict__ Mc, float* __restrict__ Lc)
{
  __shared__ float Yt[128 * 64];   // [c][m], resident
  __shared__ float Xr[128 * 64];   // overlay: XtSw (swizzled) OR red[16][65]+tileM[64]
  const int b  = blockIdx.y;
  const int m0 = blockIdx.x * 64;
  const int t  = threadIdx.x;
  const int tx = t & 15, ty = t >> 4;

#pragma unroll
  for (int k = 0; k < 32; ++k) {
    int flat = t + 256 * k;
    int c = flat >> 6, jm = flat & 63;
    Yt[c * 64 + jm] = Y[(size_t)b * CC * NN + (size_t)c * NN + m0 + jm];
  }

  float runM = -1e30f, runL = 0.0f;      // owned by threads t<64 (m = t)
  float* red   = Xr;                     // [16][65] = 1040 floats
  float* tileM = Xr + 1040;              // [64]

  int key[4];
#pragma unroll
  for (int i = 0; i < 4; ++i) key[i] = (((ty * 4 + i) & 7) << 2);

  for (int nt = 0; nt < 64; ++nt) {
    const int n0 = nt * 64;
    __syncthreads();  // protects red/tileM reads of prev iter (and first Yt fill)
#pragma unroll
    for (int k = 0; k < 32; ++k) {
      int flat = t + 256 * k;
      int c = flat & 127, jn = flat >> 7;
      Xr[jn * 128 + (c ^ ((jn & 7) << 2))] =
          X[(size_t)b * NN * CC + (size_t)(n0 + jn) * CC + c];
    }
    __syncthreads();

    float s[4][4] = {};
#pragma unroll 4
    for (int c = 0; c < 128; ++c) {
      float4 y4 = *(const float4*)&Yt[c * 64 + tx * 4];
#pragma unroll
      for (int i = 0; i < 4; ++i) {
        float a = Xr[(ty * 4 + i) * 128 + (c ^ key[i])];
        s[i][0] += a * y4.x; s[i][1] += a * y4.y;
        s[i][2] += a * y4.z; s[i][3] += a * y4.w;
      }
    }
    __syncthreads();  // Xr now dead -> overlay as red/tileM

#pragma unroll
    for (int jj = 0; jj < 4; ++jj)
      red[ty * 65 + tx * 4 + jj] =
          fmaxf(fmaxf(s[0][jj], s[1][jj]), fmaxf(s[2][jj], s[3][jj]));
    __syncthreads();
    if (t < 64) {
      float tm = -1e30f;
#pragma unroll
      for (int r = 0; r < 16; ++r) tm = fmaxf(tm, red[r * 65 + t]);
      tileM[t] = tm;
    }
    __syncthreads();
    float tM[4];
#pragma unroll
    for (int jj = 0; jj < 4; ++jj) tM[jj] = tileM[tx * 4 + jj];
#pragma unroll
    for (int jj = 0; jj < 4; ++jj) {
      float p = __expf(s[0][jj] - tM[jj]) + __expf(s[1][jj] - tM[jj]) +
                __expf(s[2][jj] - tM[jj]) + __expf(s[3][jj] - tM[jj]);
      red[ty * 65 + tx * 4 + jj] = p;
    }
    __syncthreads();
    if (t < 64) {
      float lt = 0.f;
#pragma unroll
      for (int r = 0; r < 16; ++r) lt += red[r * 65 + t];
      float tm = tileM[t];
      float nM = fmaxf(runM, tm);
      runL = runL * __expf(runM - nM) + lt * __expf(tm - nM);
      runM = nM;
    }
  }
  if (t < 64) {
    Mc[(size_t)b * NN + m0 + t] = runM;
    Lc[(size_t)b * NN + m0 + t] = runL;
  }
}

// ---------------------------------------------------------------------------
// Pass 2 (flash-style): Z[n,c] = sum_m exp(s[n,m]-Mc[m])/Lc[m] * X[m,c],
// recomputing s tile-by-tile. One block per (64-wide n tile, batch).
// ---------------------------------------------------------------------------
__global__ __launch_bounds__(256) void nl_pass2(
    const float* __restrict__ X,   // [B][N][C]
    const float* __restrict__ Y,   // [B][C][N]
    const float* __restrict__ Mc, const float* __restrict__ Lc,
    float* __restrict__ Z)         // [B][N][C]
{
  __shared__ float XnSw[128 * 64];  // swizzled A-tile, resident
  __shared__ float Pt[64 * 65];     // P round-trip (C-layout -> A-side reads)
  const int b  = blockIdx.y;
  const int n0 = blockIdx.x * 64;
  const int t  = threadIdx.x;
  const int tx = t & 15, ty = t >> 4;

#pragma unroll
  for (int k = 0; k < 32; ++k) {
    int flat = t + 256 * k;
    int c = flat & 127, jn = flat >> 7;
    XnSw[jn * 128 + (c ^ ((jn & 7) << 2))] =
        X[(size_t)b * NN * CC + (size_t)(n0 + jn) * CC + c];
  }
  __syncthreads();

  int key[4];
#pragma unroll
  for (int i = 0; i < 4; ++i) key[i] = (((ty * 4 + i) & 7) << 2);

  float z[4][8] = {};
  for (int mt = 0; mt < 64; ++mt) {
    const int m0 = mt * 64;
    float s[4][4] = {};
#pragma unroll 4
    for (int c = 0; c < 128; ++c) {
      float4 y4 = *(const float4*)&Y[(size_t)b * CC * NN + (size_t)c * NN + m0 + tx * 4];
#pragma unroll
      for (int i = 0; i < 4; ++i) {
        float a = XnSw[(ty * 4 + i) * 128 + (c ^ key[i])];
        s[i][0] += a * y4.x; s[i][1] += a * y4.y;
        s[i][2] += a * y4.z; s[i][3] += a * y4.w;
      }
    }
    float4 M4 = *(const float4*)&Mc[(size_t)b * NN + m0 + tx * 4];
    float4 L4 = *(const float4*)&Lc[(size_t)b * NN + m0 + tx * 4];
    float mv[4] = {M4.x, M4.y, M4.z, M4.w};
    float il[4] = {1.f / L4.x, 1.f / L4.y, 1.f / L4.z, 1.f / L4.w};
    __syncthreads();  // WAR: prev GEMM2 finished reading Pt
#pragma unroll
    for (int i = 0; i < 4; ++i)
#pragma unroll
      for (int jj = 0; jj < 4; ++jj)
        Pt[(ty * 4 + i) * 65 + tx * 4 + jj] = __expf(s[i][jj] - mv[jj]) * il[jj];
    __syncthreads();

    // GEMM2: z[4n][8c] += P[n][m] * X[m][c]   (same (tx,ty): c0=tx*8, n=ty*4)
#pragma unroll 2
    for (int m = 0; m < 64; ++m) {
      const float* xr = &X[(size_t)b * NN * CC + (size_t)(m0 + m) * CC + tx * 8];
      float4 xa = *(const float4*)xr;
      float4 xb = *(const float4*)(xr + 4);
#pragma unroll
      for (int i = 0; i < 4; ++i) {
        float p = Pt[(ty * 4 + i) * 65 + m];
        z[i][0] += p * xa.x; z[i][1] += p * xa.y; z[i][2] += p * xa.z; z[i][3] += p * xa.w;
        z[i][4] += p * xb.x; z[i][5] += p * xb.y; z[i][6] += p * xb.z; z[i][7] += p * xb.w;
      }
    }
  }
#pragma unroll
  for (int i = 0; i < 4; ++i) {
    float4 a = {z[i][0], z[i][1], z[i][2], z[i][3]};
    float4 bv = {z[i][4], z[i][5], z[i][6], z[i][7]};
    float* zr = &Z[(size_t)b * NN * CC + (size_t)(n0 + ty * 4 + i) * CC + tx * 8];
    *(float4*)zr = a;
    *(float4*)(zr + 4) = bv;
  }
}

// ---------------------------------------------------------------------------
// Final conv1x1: out[b][o][n] = sum_c Ww[o][c] * Z[b][n][c] + Wb[o]
// ---------------------------------------------------------------------------
__global__ __launch_bounds__(256) void nl_convw(
    const float* __restrict__ Z, const float* __restrict__ w,
    const float* __restrict__ bias, float* __restrict__ out)
{
  __shared__ float Zt[64 * 129];
  const int b  = blockIdx.y;
  const int n0 = blockIdx.x * 64;
  const int t  = threadIdx.x;
#pragma unroll
  for (int k = 0; k < 32; ++k) {
    int flat = t + 256 * k;
    int c = flat & 127, jn = flat >> 7;
    Zt[jn * 129 + c] = Z[(size_t)b * NN * CC + (size_t)(n0 + jn) * CC + c];
  }
  __syncthreads();
  const int j = t & 63, wq = t >> 6;
  float acc[32];
#pragma unroll
  for (int g = 0; g < 32; ++g) acc[g] = bias[wq * 32 + g];
  for (int c = 0; c < 128; ++c) {
    float v = Zt[j * 129 + c];  // (j+c)%32 spread -> conflict-free
#pragma unroll
    for (int g = 0; g < 32; ++g)
      acc[g] += w[(wq * 32 + g) * CC + c] * v;
  }
#pragma unroll
  for (int g = 0; g < 32; ++g)
    out[(size_t)b * CC * NN + (size_t)(wq * 32 + g) * NN + n0 + j] = acc[g];
}

// ---------------------------------------------------------------------------
extern "C" void kernel_launch(void* const* d_in, const int* in_sizes, int n_in,
                              void* d_out, int out_size, void* d_ws, size_t ws_size,
                              hipStream_t stream) {
  const float* cur     = (const float*)d_in[0];
  const float* ref     = (const float*)d_in[1];
  const float* theta_w = (const float*)d_in[2];
  const float* theta_b = (const float*)d_in[3];
  const float* phi_w   = (const float*)d_in[4];
  const float* phi_b   = (const float*)d_in[5];
  const float* Ww      = (const float*)d_in[6];
  const float* Wb      = (const float*)d_in[7];
  float* out = (float*)d_out;

  // workspace layout (floats): X | Y | Mc | Lc | Z  = 50.6 MB total
  float* Xb = (float*)d_ws;
  float* Yb = Xb + (size_t)BB * NN * CC;
  float* Mc = Yb + (size_t)BB * NN * CC;
  float* Lc = Mc + (size_t)BB * NN;
  float* Zb = Lc + (size_t)BB * NN;

  dim3 grid(NN / 64, BB), blk(256);
  nl_conv_in<<<grid, blk, 0, stream>>>(ref, theta_w, theta_b, Xb, 1);  // X[b][n][c]
  nl_conv_in<<<grid, blk, 0, stream>>>(cur, phi_w,   phi_b,   Yb, 0);  // Y[b][c][m]
  nl_stats <<<grid, blk, 0, stream>>>(Xb, Yb, Mc, Lc);
  nl_pass2 <<<grid, blk, 0, stream>>>(Xb, Yb, Mc, Lc, Zb);
  nl_convw <<<grid, blk, 0, stream>>>(Zb, Ww, Wb, out);
}

// Round 2
// 987.898 us; speedup vs baseline: 2.6295x; 2.6295x over previous
//
#include <hip/hip_runtime.h>
#include <hip/hip_bf16.h>

#define BB 8
#define CC 128
#define NN 4096  // H*W = 64*64

typedef __attribute__((ext_vector_type(8))) short bf16x8;  // 8 bf16 = 4 VGPRs
typedef __attribute__((ext_vector_type(4))) float f32x4;

// float -> bf16 (RNE), bit-level
static __device__ __forceinline__ unsigned short f2bfu(float f) {
  unsigned int x = __float_as_uint(f);
  x += 0x7fffu + ((x >> 16) & 1u);
  return (unsigned short)(x >> 16);
}

// ---------------------------------------------------------------------------
// conv1x1 input stage: res = w @ in + bias per position, emitted as bf16.
// in:  [B][C][N] fp32
// out_nc: bf16 [B][N][C]  (always)
// out_cn: bf16 [B][C][N]  (if non-null; needed for theta: PV B-operand)
// ---------------------------------------------------------------------------
__global__ __launch_bounds__(256) void nl_conv_bf16(
    const float* __restrict__ in, const float* __restrict__ w,
    const float* __restrict__ bias, unsigned short* __restrict__ out_nc,
    unsigned short* __restrict__ out_cn)
{
  __shared__ float sm[64 * 129];  // overlay: in_t[128][64] then out_t[64][129]
  const int b  = blockIdx.y;
  const int n0 = blockIdx.x * 64;
  const int t  = threadIdx.x;

#pragma unroll
  for (int k = 0; k < 32; ++k) {
    int flat = t + 256 * k;          // 8192 elements
    int c = flat >> 6, j = flat & 63;
    sm[c * 64 + j] = in[(size_t)b * CC * NN + (size_t)c * NN + n0 + j];
  }
  __syncthreads();

  const int j = t & 63, wq = t >> 6;  // wave-uniform wq
  float acc[32];
#pragma unroll
  for (int g = 0; g < 32; ++g) acc[g] = bias[wq * 32 + g];
  for (int cp = 0; cp < 128; ++cp) {
    float v = sm[cp * 64 + j];        // lanes j -> conflict-free
#pragma unroll
    for (int g = 0; g < 32; ++g)
      acc[g] += w[(wq * 32 + g) * CC + cp] * v;  // wave-uniform w read
  }
  __syncthreads();
#pragma unroll
  for (int g = 0; g < 32; ++g) sm[j * 129 + wq * 32 + g] = acc[g];
  __syncthreads();

  // [N][C] bf16, packed pairs (4B stores, coalesced)
#pragma unroll
  for (int k = 0; k < 16; ++k) {
    int flat = t + 256 * k;           // 4096 pairs
    int cp = flat & 63, jj = flat >> 6;
    float f0 = sm[jj * 129 + cp * 2], f1 = sm[jj * 129 + cp * 2 + 1];
    unsigned int pk = (unsigned int)f2bfu(f0) | ((unsigned int)f2bfu(f1) << 16);
    *(unsigned int*)(out_nc + ((size_t)b * NN + n0 + jj) * CC + cp * 2) = pk;
  }
  if (out_cn) {
    // [C][N] bf16, packed n-pairs
#pragma unroll
    for (int k = 0; k < 16; ++k) {
      int flat = t + 256 * k;
      int jp = flat & 31, c = flat >> 5;
      float f0 = sm[(jp * 2) * 129 + c], f1 = sm[(jp * 2 + 1) * 129 + c];
      unsigned int pk = (unsigned int)f2bfu(f0) | ((unsigned int)f2bfu(f1) << 16);
      *(unsigned int*)(out_cn + ((size_t)b * CC + c) * NN + n0 + jp * 2) = pk;
    }
  }
}

// ---------------------------------------------------------------------------
// Pass 1 (MFMA): per-column softmax stats over n for each cur-position m.
// s[n,m] = sum_c X[n,c]*Y[m,c] (Ync stored m-major = B^T pattern).
// Wave-private 16-wide m-tile; online (M,L) merge; NO LDS, NO barriers.
// ---------------------------------------------------------------------------
__global__ __launch_bounds__(256) void nl_stats_mfma(
    const unsigned short* __restrict__ Xnc, const unsigned short* __restrict__ Ync,
    float* __restrict__ Mc, float* __restrict__ Lc)
{
  const int b = blockIdx.y;
  const int t = threadIdx.x;
  const int wave = t >> 6, lane = t & 63, q = lane >> 4, r = lane & 15;
  const int m0 = blockIdx.x * 64 + wave * 16;

  // B fragments: lane holds B[k=c][col=m] = Ync[m0+r][q*8+j], constant over n loop
  const size_t yb = ((size_t)b * NN + m0 + r) * CC + q * 8;
  bf16x8 bf[4];
#pragma unroll
  for (int k = 0; k < 4; ++k) bf[k] = *(const bf16x8*)(Ync + yb + k * 32);

  float runM = -1e30f, runL = 0.0f;
  for (int nt = 0; nt < 64; ++nt) {
    const size_t xb = ((size_t)b * NN + nt * 64 + r) * CC + q * 8;
    bf16x8 af[4][4];
#pragma unroll
    for (int sub = 0; sub < 4; ++sub)
#pragma unroll
      for (int k = 0; k < 4; ++k)
        af[sub][k] = *(const bf16x8*)(Xnc + xb + (size_t)sub * 16 * CC + k * 32);

    f32x4 acc[4];
#pragma unroll
    for (int sub = 0; sub < 4; ++sub) {
      acc[sub] = (f32x4){0.f, 0.f, 0.f, 0.f};
#pragma unroll
      for (int k = 0; k < 4; ++k)
        acc[sub] = __builtin_amdgcn_mfma_f32_16x16x32_bf16(af[sub][k], bf[k], acc[sub], 0, 0, 0);
    }
    // column (m) stats: col=lane&15, rows spread over quads+regs+subs
    float tm = -1e30f;
#pragma unroll
    for (int sub = 0; sub < 4; ++sub)
#pragma unroll
      for (int rg = 0; rg < 4; ++rg) tm = fmaxf(tm, acc[sub][rg]);
    tm = fmaxf(tm, __shfl_xor(tm, 16));
    tm = fmaxf(tm, __shfl_xor(tm, 32));
    float nM = fmaxf(runM, tm);
    float ts = 0.f;
#pragma unroll
    for (int sub = 0; sub < 4; ++sub)
#pragma unroll
      for (int rg = 0; rg < 4; ++rg) ts += __expf(acc[sub][rg] - nM);
    ts += __shfl_xor(ts, 16);
    ts += __shfl_xor(ts, 32);
    runL = runL * __expf(runM - nM) + ts;
    runM = nM;
  }
  if (lane < 16) {
    Mc[(size_t)b * NN + m0 + lane] = runM;
    Lc[(size_t)b * NN + m0 + lane] = runL;
  }
}

// ---------------------------------------------------------------------------
// Pass 2 (MFMA, flash-style): Z[n,c] = sum_m exp(s[n,m]-Mc[m])/Lc[m] * X[m,c].
// S recomputed with the IDENTICAL mfma chain as stats (so s<=Mc exactly).
// P: C-layout -> A-layout via wave-private LDS tile (16x72, 16B-aligned rows).
// NO __syncthreads anywhere (all LDS is wave-private, in-order via lgkmcnt).
// ---------------------------------------------------------------------------
__global__ __launch_bounds__(256) void nl_pass2_mfma(
    const unsigned short* __restrict__ Xnc, const unsigned short* __restrict__ Ync,
    const unsigned short* __restrict__ Xcn,
    const float* __restrict__ Mc, const float* __restrict__ Lc,
    float* __restrict__ Z)
{
  __shared__ unsigned short P[4][16 * 72];  // per-wave 2.25 KB, stride 72 el = 144 B
  const int b = blockIdx.y;
  const int t = threadIdx.x;
  const int wave = t >> 6, lane = t & 63, q = lane >> 4, r = lane & 15;
  const int n0 = blockIdx.x * 64 + wave * 16;
  unsigned short* Pw = P[wave];

  // A fragments for S: rows = this wave's 16 n, constant over whole m loop
  const size_t xb = ((size_t)b * NN + n0 + r) * CC + q * 8;
  bf16x8 af[4];
#pragma unroll
  for (int k = 0; k < 4; ++k) af[k] = *(const bf16x8*)(Xnc + xb + k * 32);

  f32x4 z[8];
#pragma unroll
  for (int ct = 0; ct < 8; ++ct) z[ct] = (f32x4){0.f, 0.f, 0.f, 0.f};

  for (int mt = 0; mt < 64; ++mt) {
    const int m0 = mt * 64;
    // ---- S tiles: 4 m-subtiles of 16 ----
    f32x4 s[4];
#pragma unroll
    for (int ms = 0; ms < 4; ++ms) {
      const size_t yb = ((size_t)b * NN + m0 + ms * 16 + r) * CC + q * 8;
      bf16x8 b0 = *(const bf16x8*)(Ync + yb);
      bf16x8 b1 = *(const bf16x8*)(Ync + yb + 32);
      bf16x8 b2 = *(const bf16x8*)(Ync + yb + 64);
      bf16x8 b3 = *(const bf16x8*)(Ync + yb + 96);
      f32x4 a = (f32x4){0.f, 0.f, 0.f, 0.f};
      a = __builtin_amdgcn_mfma_f32_16x16x32_bf16(af[0], b0, a, 0, 0, 0);
      a = __builtin_amdgcn_mfma_f32_16x16x32_bf16(af[1], b1, a, 0, 0, 0);
      a = __builtin_amdgcn_mfma_f32_16x16x32_bf16(af[2], b2, a, 0, 0, 0);
      a = __builtin_amdgcn_mfma_f32_16x16x32_bf16(af[3], b3, a, 0, 0, 0);
      s[ms] = a;
    }
    // ---- P = exp(s-M)/L, C-layout -> LDS [n][m] bf16 ----
#pragma unroll
    for (int ms = 0; ms < 4; ++ms) {
      const size_t mcol = (size_t)b * NN + m0 + ms * 16 + r;  // col = lane&15
      float Mv = Mc[mcol];
      float il = 1.f / Lc[mcol];
#pragma unroll
      for (int rg = 0; rg < 4; ++rg) {
        float p = __expf(s[ms][rg] - Mv) * il;
        Pw[(q * 4 + rg) * 72 + ms * 16 + r] = f2bfu(p);
      }
    }
    // ---- PV: Z[16n x 128c] += P[16n x 64m] * X[64m x 128c] ----
#pragma unroll
    for (int k2 = 0; k2 < 2; ++k2) {
      // A-operand: lane holds P[n=lane&15][m_local=k2*32+q*8+j], contiguous 16B
      bf16x8 ap = *(const bf16x8*)(Pw + r * 72 + k2 * 32 + q * 8);
#pragma unroll
      for (int ct = 0; ct < 8; ++ct) {
        // B-operand: lane holds X[m=m0+k2*32+q*8+j][c=ct*16+r] from Xcn [C][N]
        const size_t cb = ((size_t)b * CC + ct * 16 + r) * NN + m0 + k2 * 32 + q * 8;
        bf16x8 bv = *(const bf16x8*)(Xcn + cb);
        z[ct] = __builtin_amdgcn_mfma_f32_16x16x32_bf16(ap, bv, z[ct], 0, 0, 0);
      }
    }
  }
  // epilogue: C-layout (row=q*4+rg, col=lane&15) -> Z fp32 [B][N][C]
#pragma unroll
  for (int ct = 0; ct < 8; ++ct)
#pragma unroll
    for (int rg = 0; rg < 4; ++rg)
      Z[((size_t)b * NN + n0 + q * 4 + rg) * CC + ct * 16 + r] = z[ct][rg];
}

// ---------------------------------------------------------------------------
// Final conv1x1: out[b][o][n] = sum_c Ww[o][c] * Z[b][n][c] + Wb[o]  (fp32)
// ---------------------------------------------------------------------------
__global__ __launch_bounds__(256) void nl_convw(
    const float* __restrict__ Z, const float* __restrict__ w,
    const float* __restrict__ bias, float* __restrict__ out)
{
  __shared__ float Zt[64 * 129];
  const int b  = blockIdx.y;
  const int n0 = blockIdx.x * 64;
  const int t  = threadIdx.x;
#pragma unroll
  for (int k = 0; k < 32; ++k) {
    int flat = t + 256 * k;
    int c = flat & 127, jn = flat >> 7;
    Zt[jn * 129 + c] = Z[(size_t)b * NN * CC + (size_t)(n0 + jn) * CC + c];
  }
  __syncthreads();
  const int j = t & 63, wq = t >> 6;
  float acc[32];
#pragma unroll
  for (int g = 0; g < 32; ++g) acc[g] = bias[wq * 32 + g];
  for (int c = 0; c < 128; ++c) {
    float v = Zt[j * 129 + c];
#pragma unroll
    for (int g = 0; g < 32; ++g)
      acc[g] += w[(wq * 32 + g) * CC + c] * v;
  }
#pragma unroll
  for (int g = 0; g < 32; ++g)
    out[(size_t)b * CC * NN + (size_t)(wq * 32 + g) * NN + n0 + j] = acc[g];
}

// ---------------------------------------------------------------------------
extern "C" void kernel_launch(void* const* d_in, const int* in_sizes, int n_in,
                              void* d_out, int out_size, void* d_ws, size_t ws_size,
                              hipStream_t stream) {
  const float* cur     = (const float*)d_in[0];
  const float* ref     = (const float*)d_in[1];
  const float* theta_w = (const float*)d_in[2];
  const float* theta_b = (const float*)d_in[3];
  const float* phi_w   = (const float*)d_in[4];
  const float* phi_b   = (const float*)d_in[5];
  const float* Ww      = (const float*)d_in[6];
  const float* Wb      = (const float*)d_in[7];
  float* out = (float*)d_out;

  // ws layout: Xnc(bf16 8MB) | Ync(bf16 8MB) | Xcn(bf16 8MB) | Mc | Lc | Z(fp32 16MB)
  unsigned short* Xnc = (unsigned short*)d_ws;
  unsigned short* Ync = Xnc + (size_t)BB * NN * CC;
  unsigned short* Xcn = Ync + (size_t)BB * NN * CC;
  float* Mc = (float*)(Xcn + (size_t)BB * NN * CC);
  float* Lc = Mc + (size_t)BB * NN;
  float* Zb = Lc + (size_t)BB * NN;

  dim3 grid(NN / 64, BB), blk(256);
  nl_conv_bf16 <<<grid, blk, 0, stream>>>(ref, theta_w, theta_b, Xnc, Xcn);  // x = theta(ref)
  nl_conv_bf16 <<<grid, blk, 0, stream>>>(cur, phi_w,   phi_b,   Ync, nullptr);  // y = phi(cur)
  nl_stats_mfma<<<grid, blk, 0, stream>>>(Xnc, Ync, Mc, Lc);
  nl_pass2_mfma<<<grid, blk, 0, stream>>>(Xnc, Ync, Xcn, Mc, Lc, Zb);
  nl_convw     <<<grid, blk, 0, stream>>>(Zb, Ww, Wb, out);
}

// Round 3
// 349.742 us; speedup vs baseline: 7.4274x; 2.8247x over previous
//
#include <hip/hip_runtime.h>
#include <hip/hip_bf16.h>

#define BB 8
#define CC 128
#define NN 4096  // H*W = 64*64

typedef __attribute__((ext_vector_type(8))) short bf16x8;   // 8 bf16 = 4 VGPRs
typedef __attribute__((ext_vector_type(4))) float f32x4;
typedef __attribute__((ext_vector_type(16))) float f32x16;

static __device__ __forceinline__ unsigned short f2bfu(float f) {
  unsigned int x = __float_as_uint(f);
  x += 0x7fffu + ((x >> 16) & 1u);
  return (unsigned short)(x >> 16);
}
static __device__ __forceinline__ f32x16 zero16() {
  f32x16 z;
#pragma unroll
  for (int i = 0; i < 16; ++i) z[i] = 0.f;
  return z;
}

// async global->LDS, 16B per lane; LDS dest must be wave-uniform base.
#define GLD16(gp, lp)                                                     \
  __builtin_amdgcn_global_load_lds(                                       \
      (const __attribute__((address_space(1))) unsigned int*)(gp),        \
      (__attribute__((address_space(3))) unsigned int*)(lp), 16, 0, 0)

// ---------------------------------------------------------------------------
// conv1x1 input stage: res = w @ in + bias per position, emitted as bf16.
// Weight reads forced scalar via readfirstlane (s_load path).
// ---------------------------------------------------------------------------
__global__ __launch_bounds__(256) void nl_conv_bf16(
    const float* __restrict__ in, const float* __restrict__ w,
    const float* __restrict__ bias, unsigned short* __restrict__ out_nc,
    unsigned short* __restrict__ out_cn)
{
  __shared__ float sm[64 * 129];  // overlay: in_t[128][64] then out_t[64][129]
  const int b  = blockIdx.y;
  const int n0 = blockIdx.x * 64;
  const int t  = threadIdx.x;

#pragma unroll
  for (int k = 0; k < 32; ++k) {
    int flat = t + 256 * k;          // 8192 elements
    int c = flat >> 6, j = flat & 63;
    sm[c * 64 + j] = in[(size_t)b * CC * NN + (size_t)c * NN + n0 + j];
  }
  __syncthreads();

  const int j = t & 63;
  const int wqs = __builtin_amdgcn_readfirstlane(t >> 6);  // wave-uniform
  float acc[32];
#pragma unroll
  for (int g = 0; g < 32; ++g) acc[g] = bias[wqs * 32 + g];
  for (int cp4 = 0; cp4 < 32; ++cp4) {
    float v0 = sm[(cp4 * 4 + 0) * 64 + j];
    float v1 = sm[(cp4 * 4 + 1) * 64 + j];
    float v2 = sm[(cp4 * 4 + 2) * 64 + j];
    float v3 = sm[(cp4 * 4 + 3) * 64 + j];
#pragma unroll
    for (int g = 0; g < 32; ++g) {
      float4 wv = *(const float4*)&w[(wqs * 32 + g) * CC + cp4 * 4];
      acc[g] = fmaf(wv.x, v0, fmaf(wv.y, v1, fmaf(wv.z, v2, fmaf(wv.w, v3, acc[g]))));
    }
  }
  __syncthreads();
#pragma unroll
  for (int g = 0; g < 32; ++g) sm[j * 129 + wqs * 32 + g] = acc[g];
  __syncthreads();

#pragma unroll
  for (int k = 0; k < 16; ++k) {
    int flat = t + 256 * k;           // 4096 bf16-pairs, [N][C]
    int cp = flat & 63, jj = flat >> 6;
    float f0 = sm[jj * 129 + cp * 2], f1 = sm[jj * 129 + cp * 2 + 1];
    unsigned int pk = (unsigned int)f2bfu(f0) | ((unsigned int)f2bfu(f1) << 16);
    *(unsigned int*)(out_nc + ((size_t)b * NN + n0 + jj) * CC + cp * 2) = pk;
  }
  if (out_cn) {
#pragma unroll
    for (int k = 0; k < 16; ++k) {
      int flat = t + 256 * k;         // [C][N], packed n-pairs
      int jp = flat & 31, c = flat >> 5;
      float f0 = sm[(jp * 2) * 129 + c], f1 = sm[(jp * 2 + 1) * 129 + c];
      unsigned int pk = (unsigned int)f2bfu(f0) | ((unsigned int)f2bfu(f1) << 16);
      *(unsigned int*)(out_cn + ((size_t)b * CC + c) * NN + n0 + jp * 2) = pk;
    }
  }
}

// ---------------------------------------------------------------------------
// Pass 1 (MFMA 32x32x16, LDS-staged): per-m softmax stats over an n-half.
// Block: m-strip 64, n-half 2048. 4 waves: wave = nh*2+mq -> S[32n][32m].
// A (X rows) streamed via swizzled LDS tile; B (Y cols) pinned in registers.
// ---------------------------------------------------------------------------
__global__ __launch_bounds__(256) void nl_stats2(
    const unsigned short* __restrict__ Xnc, const unsigned short* __restrict__ Ync,
    float* __restrict__ Mpart, float* __restrict__ Lpart)
{
  __shared__ unsigned short Xt[64 * 128];  // 16 KB, [n][c], chunk^= (row&7)
  __shared__ float mM[128], mL[128];
  const int b = blockIdx.z, nhalf = blockIdx.y, mstrip = blockIdx.x;
  const int t = threadIdx.x;
  const int wave = t >> 6, lane = t & 63, q2 = lane >> 5, cm = lane & 31;
  const int mq = wave & 1, nh = wave >> 1;
  const int mcol = mstrip * 64 + mq * 32 + cm;

  // B fragments (Y, own 32 m): loaded once.  B[k=c][col=m]
  bf16x8 bf[8];
  const unsigned short* yb = Ync + ((size_t)b * NN + mcol) * CC + q2 * 8;
#pragma unroll
  for (int k = 0; k < 8; ++k) bf[k] = *(const bf16x8*)(yb + k * 16);

  float runM = -1e30f, runL = 0.0f;
  for (int nt = 0; nt < 32; ++nt) {
    const int n0 = nhalf * 2048 + nt * 64;
    __syncthreads();  // Xt free
#pragma unroll
    for (int i = 0; i < 4; ++i) {
      int slot = i * 256 + t;
      int row = slot >> 4, g = (slot & 15) ^ (row & 7);
      const unsigned short* ga = Xnc + ((size_t)b * NN + n0 + row) * CC + g * 8;
      GLD16(ga, Xt + i * 2048 + wave * 512);
    }
    __syncthreads();  // staged (vmcnt drained by barrier)

    f32x16 acc = zero16();
#pragma unroll
    for (int kstep = 0; kstep < 8; ++kstep) {
      int arow = nh * 32 + cm;
      int phys = (kstep * 2 + q2) ^ (cm & 7);
      bf16x8 av = *(const bf16x8*)&Xt[arow * 128 + phys * 8];
      acc = __builtin_amdgcn_mfma_f32_32x32x16_bf16(av, bf[kstep], acc, 0, 0, 0);
    }
    // per-column stats (col = m = lane&31; rows spread over regs + q2)
    float tm = -1e30f;
#pragma unroll
    for (int rg = 0; rg < 16; ++rg) tm = fmaxf(tm, acc[rg]);
    tm = fmaxf(tm, __shfl_xor(tm, 32));
    float nM = fmaxf(runM, tm);
    float ts = 0.f;
#pragma unroll
    for (int rg = 0; rg < 16; ++rg) ts += __expf(acc[rg] - nM);
    ts += __shfl_xor(ts, 32);
    runL = runL * __expf(runM - nM) + ts;
    runM = nM;
  }
  // cross-wave merge: waves mq (nh=0) and 2+mq (nh=1) share m columns.
  if (q2 == 0) { mM[wave * 32 + cm] = runM; mL[wave * 32 + cm] = runL; }
  __syncthreads();
  if (t < 64) {
    int mqq = t >> 5, cmm = t & 31;
    float Ma = mM[mqq * 32 + cmm],       La = mL[mqq * 32 + cmm];
    float Mb = mM[(2 + mqq) * 32 + cmm], Lb = mL[(2 + mqq) * 32 + cmm];
    float M = fmaxf(Ma, Mb);
    float L = La * __expf(Ma - M) + Lb * __expf(Mb - M);
    size_t o = ((size_t)nhalf * BB + b) * NN + mstrip * 64 + t;
    Mpart[o] = M; Lpart[o] = L;
  }
}

// merge the two n-half partials -> Mc, iLc
__global__ __launch_bounds__(256) void nl_merge(
    const float* __restrict__ Mp, const float* __restrict__ Lp,
    float* __restrict__ Mc, float* __restrict__ iLc)
{
  size_t i = (size_t)blockIdx.x * 256 + threadIdx.x;  // BB*NN
  float M0 = Mp[i], M1 = Mp[(size_t)BB * NN + i];
  float L0 = Lp[i], L1 = Lp[(size_t)BB * NN + i];
  float M = fmaxf(M0, M1);
  float L = L0 * __expf(M0 - M) + L1 * __expf(M1 - M);
  Mc[i] = M; iLc[i] = 1.0f / L;
}

// ---------------------------------------------------------------------------
// Pass 2 (MFMA 32x32x16, LDS-staged, flash-style): Zpart[n,c] over an m-half.
// Block: n-strip 128, m-half 2048; 32 iters of m-tile 64.
// S phase: wave nq -> S[32n][64m] (A=X regs, B=Y from LDS), exp -> P LDS.
// PV phase: wave (nh,ch) -> Z[64n][64c] 2x2 blocking (A=P, B=Xcn from LDS).
// ---------------------------------------------------------------------------
__global__ __launch_bounds__(256) void nl_pass2b(
    const unsigned short* __restrict__ Xnc, const unsigned short* __restrict__ Ync,
    const unsigned short* __restrict__ Xcn,
    const float* __restrict__ Mc, const float* __restrict__ iLc,
    float* __restrict__ Zpart)
{
  __shared__ unsigned short Yt[64 * 128];   // [m][c] 16 KB, chunk^= (m&7)
  __shared__ unsigned short Xt[128 * 64];   // [c][m] 16 KB, chunk^= (c&7)
  __shared__ unsigned short Pt[128 * 64];   // [n][m] 16 KB, chunk^= (n&7)
  const int b = blockIdx.z, mhalf = blockIdx.y, nstrip = blockIdx.x;
  const int t = threadIdx.x;
  const int wave = t >> 6, lane = t & 63, q2 = lane >> 5, cm = lane & 31;
  const int nh = wave & 1, ch = wave >> 1;

  // A fragments (X, own 32 n rows for S phase): loaded once. A[row=n][k=c]
  const int nrowA = nstrip * 128 + wave * 32 + cm;
  bf16x8 af[8];
  const unsigned short* xb = Xnc + ((size_t)b * NN + nrowA) * CC + q2 * 8;
#pragma unroll
  for (int k = 0; k < 8; ++k) af[k] = *(const bf16x8*)(xb + k * 16);

  f32x16 z[2][2];
  z[0][0] = zero16(); z[0][1] = zero16(); z[1][0] = zero16(); z[1][1] = zero16();

  const float* McB = Mc + (size_t)b * NN;
  const float* iLB = iLc + (size_t)b * NN;

  for (int mt = 0; mt < 32; ++mt) {
    const int m0g = mhalf * 2048 + mt * 64;
    __syncthreads();  // tiles + Pt free (prev iter fully consumed)
#pragma unroll
    for (int i = 0; i < 4; ++i) {     // stage Yt: rows = m, 16 chunks of c
      int slot = i * 256 + t;
      int row = slot >> 4, g = (slot & 15) ^ (row & 7);
      const unsigned short* ga = Ync + ((size_t)b * NN + m0g + row) * CC + g * 8;
      GLD16(ga, Yt + i * 2048 + wave * 512);
    }
#pragma unroll
    for (int i = 0; i < 4; ++i) {     // stage Xt: rows = c, 8 chunks of m
      int slot = i * 256 + t;
      int row = slot >> 3, g = (slot & 7) ^ (row & 7);
      const unsigned short* ga = Xcn + ((size_t)b * CC + row) * NN + m0g + g * 8;
      GLD16(ga, Xt + i * 2048 + wave * 512);
    }
    __syncthreads();  // staged

    // ---- S phase: wave covers rows wave*32, cols m0g..m0g+64 ----
#pragma unroll
    for (int msub = 0; msub < 2; ++msub) {
      f32x16 s = zero16();
#pragma unroll
      for (int kstep = 0; kstep < 8; ++kstep) {
        int brow = msub * 32 + cm;
        int phys = (kstep * 2 + q2) ^ (cm & 7);
        bf16x8 bv = *(const bf16x8*)&Yt[brow * 128 + phys * 8];
        s = __builtin_amdgcn_mfma_f32_32x32x16_bf16(af[kstep], bv, s, 0, 0, 0);
      }
      int mg = m0g + msub * 32 + cm;   // col = m
      float Mv = McB[mg], il = iLB[mg];
#pragma unroll
      for (int rg = 0; rg < 16; ++rg) {
        int nrow = wave * 32 + (rg & 3) + 8 * (rg >> 2) + 4 * q2;
        float p = __expf(s[rg] - Mv) * il;
        int phys = (msub * 4 + (cm >> 3)) ^ (nrow & 7);
        Pt[nrow * 64 + phys * 8 + (cm & 7)] = f2bfu(p);
      }
    }
    __syncthreads();  // Pt ready

    // ---- PV phase: wave (nh,ch), Z[64n][64c], K=64 over this m-tile ----
#pragma unroll
    for (int kstep = 0; kstep < 4; ++kstep) {
      bf16x8 pa[2], xv[2];
#pragma unroll
      for (int s2 = 0; s2 < 2; ++s2) {
        int arow = nh * 64 + s2 * 32 + cm;
        int pphys = (kstep * 2 + q2) ^ (cm & 7);
        pa[s2] = *(const bf16x8*)&Pt[arow * 64 + pphys * 8];
        int brow = ch * 64 + s2 * 32 + cm;
        xv[s2] = *(const bf16x8*)&Xt[brow * 64 + pphys * 8];
      }
#pragma unroll
      for (int i = 0; i < 2; ++i)
#pragma unroll
        for (int jj = 0; jj < 2; ++jj)
          z[i][jj] = __builtin_amdgcn_mfma_f32_32x32x16_bf16(pa[i], xv[jj], z[i][jj], 0, 0, 0);
    }
  }

  // epilogue: Zpart[mhalf][b][n][c]
  float* Zp = Zpart + ((size_t)mhalf * BB + b) * NN * CC;
#pragma unroll
  for (int i = 0; i < 2; ++i)
#pragma unroll
    for (int jj = 0; jj < 2; ++jj)
#pragma unroll
      for (int rg = 0; rg < 16; ++rg) {
        int nrow = nstrip * 128 + nh * 64 + i * 32 + (rg & 3) + 8 * (rg >> 2) + 4 * q2;
        int ccol = ch * 64 + jj * 32 + cm;
        Zp[(size_t)nrow * CC + ccol] = z[i][jj][rg];
      }
}

// ---------------------------------------------------------------------------
// Final conv1x1 over Z = Zpart0 + Zpart1 (fp32), scalar weight loads.
// ---------------------------------------------------------------------------
__global__ __launch_bounds__(256) void nl_convw(
    const float* __restrict__ Zpart, const float* __restrict__ w,
    const float* __restrict__ bias, float* __restrict__ out)
{
  __shared__ float Zt[64 * 132];
  const int b  = blockIdx.y;
  const int n0 = blockIdx.x * 64;
  const int t  = threadIdx.x;
  const float* Zp0 = Zpart + (size_t)b * NN * CC;
  const float* Zp1 = Zpart + ((size_t)BB + b) * NN * CC;
#pragma unroll
  for (int k = 0; k < 32; ++k) {
    int flat = t + 256 * k;
    int c = flat & 127, jn = flat >> 7;
    size_t idx = (size_t)(n0 + jn) * CC + c;
    Zt[jn * 132 + c] = Zp0[idx] + Zp1[idx];
  }
  __syncthreads();
  const int j = t & 63;
  const int wqs = __builtin_amdgcn_readfirstlane(t >> 6);
  float acc[32];
#pragma unroll
  for (int g = 0; g < 32; ++g) acc[g] = bias[wqs * 32 + g];
  for (int cp4 = 0; cp4 < 32; ++cp4) {
    float4 v = *(const float4*)&Zt[j * 132 + cp4 * 4];
#pragma unroll
    for (int g = 0; g < 32; ++g) {
      float4 wv = *(const float4*)&w[(wqs * 32 + g) * CC + cp4 * 4];
      acc[g] = fmaf(wv.x, v.x, fmaf(wv.y, v.y, fmaf(wv.z, v.z, fmaf(wv.w, v.w, acc[g]))));
    }
  }
#pragma unroll
  for (int g = 0; g < 32; ++g)
    out[(size_t)b * CC * NN + (size_t)(wqs * 32 + g) * NN + n0 + j] = acc[g];
}

// ---------------------------------------------------------------------------
extern "C" void kernel_launch(void* const* d_in, const int* in_sizes, int n_in,
                              void* d_out, int out_size, void* d_ws, size_t ws_size,
                              hipStream_t stream) {
  const float* cur     = (const float*)d_in[0];
  const float* ref     = (const float*)d_in[1];
  const float* theta_w = (const float*)d_in[2];
  const float* theta_b = (const float*)d_in[3];
  const float* phi_w   = (const float*)d_in[4];
  const float* phi_b   = (const float*)d_in[5];
  const float* Ww      = (const float*)d_in[6];
  const float* Wb      = (const float*)d_in[7];
  float* out = (float*)d_out;

  // ws: Xnc|Ync|Xcn bf16 (8MB each) | Mpart|Lpart (2*BB*NN f32) | Mc|iLc | Zpart (2*BB*NN*CC f32)
  unsigned short* Xnc = (unsigned short*)d_ws;
  unsigned short* Ync = Xnc + (size_t)BB * NN * CC;
  unsigned short* Xcn = Ync + (size_t)BB * NN * CC;
  float* Mpart = (float*)(Xcn + (size_t)BB * NN * CC);
  float* Lpart = Mpart + (size_t)2 * BB * NN;
  float* Mc    = Lpart + (size_t)2 * BB * NN;
  float* iLc   = Mc + (size_t)BB * NN;
  float* Zpart = iLc + (size_t)BB * NN;

  dim3 blk(256);
  nl_conv_bf16<<<dim3(64, BB), blk, 0, stream>>>(ref, theta_w, theta_b, Xnc, Xcn);
  nl_conv_bf16<<<dim3(64, BB), blk, 0, stream>>>(cur, phi_w, phi_b, Ync, nullptr);
  nl_stats2   <<<dim3(64, 2, BB), blk, 0, stream>>>(Xnc, Ync, Mpart, Lpart);
  nl_merge    <<<dim3(BB * NN / 256), blk, 0, stream>>>(Mpart, Lpart, Mc, iLc);
  nl_pass2b   <<<dim3(32, 2, BB), blk, 0, stream>>>(Xnc, Ync, Xcn, Mc, iLc, Zpart);
  nl_convw    <<<dim3(64, BB), blk, 0, stream>>>(Zpart, Ww, Wb, out);
}